// Round 2
// baseline (125.352 us; speedup 1.0000x reference)
//
#include <hip/hip_runtime.h>
#include <math.h>

// (T, B, D) = (1024, 16, 1024); C = B*D = 16384 independent column scans
// y[t] = beta * y[t-1] + x[t],  beta = sigmoid(beta_param)
#define T_DIM    1024
#define C_DIM    16384
#define CHUNKS   16
#define LROWS    64          // T_DIM / CHUNKS
#define COLTILES 16
#define TILE_COLS 1024       // C_DIM / COLTILES -> 4 KiB contiguous per row
#define NTHREADS 256         // 256 threads x float4 = 1024 cols

__device__ __forceinline__ float sigmoid_(float v) {
    return 1.0f / (1.0f + expf(-v));
}

// K1: per (col-tile, T-chunk) block, compute the chunk-local decayed sum
// carry[c][col] = sum_{t in chunk} beta^(end-t) x[t]  (scan value at chunk end)
__global__ __launch_bounds__(NTHREADS, 4)
void k1_carries(const float* __restrict__ x,
                const float* __restrict__ beta_p,
                float* __restrict__ carry) {
    const int tile = blockIdx.x & (COLTILES - 1);
    const int c    = blockIdx.x >> 4;                 // / COLTILES
    const int col  = tile * TILE_COLS + (threadIdx.x << 2);
    const float beta = sigmoid_(beta_p[0]);

    const float4* xp = (const float4*)(x + (size_t)(c * LROWS) * C_DIM + col);
    float4 run = make_float4(0.f, 0.f, 0.f, 0.f);
#pragma unroll 16
    for (int t = 0; t < LROWS; ++t) {
        float4 v = xp[(size_t)t * (C_DIM / 4)];
        run.x = fmaf(run.x, beta, v.x);
        run.y = fmaf(run.y, beta, v.y);
        run.z = fmaf(run.z, beta, v.z);
        run.w = fmaf(run.w, beta, v.w);
    }
    *(float4*)(carry + (size_t)c * C_DIM + col) = run;
}

// K2: fold preceding chunk carries into a per-column prefix, then stream the
// chunk: run = beta*run + x[t], store.
__global__ __launch_bounds__(NTHREADS, 4)
void k2_apply(const float* __restrict__ x,
              const float* __restrict__ beta_p,
              const float* __restrict__ carry,
              float* __restrict__ out) {
    const int tile = blockIdx.x & (COLTILES - 1);
    const int c    = blockIdx.x >> 4;
    const int col  = tile * TILE_COLS + (threadIdx.x << 2);
    const float beta = sigmoid_(beta_p[0]);

    float bL = beta;                 // beta^64 via 6 squarings
#pragma unroll
    for (int i = 0; i < 6; ++i) bL *= bL;

    // Y = full-scan value at the row just before this chunk:
    // Y_c = sum_{u<c} (beta^64)^(c-1-u) * carry[u]
    float4 Y = make_float4(0.f, 0.f, 0.f, 0.f);
    for (int u = 0; u < c; ++u) {    // wave-uniform trip count (<= 15)
        float4 cv = *(const float4*)(carry + (size_t)u * C_DIM + col);
        Y.x = fmaf(Y.x, bL, cv.x);
        Y.y = fmaf(Y.y, bL, cv.y);
        Y.z = fmaf(Y.z, bL, cv.z);
        Y.w = fmaf(Y.w, bL, cv.w);
    }

    const float4* xp = (const float4*)(x + (size_t)(c * LROWS) * C_DIM + col);
    float4*       op = (float4*)(out + (size_t)(c * LROWS) * C_DIM + col);
    float4 run = Y;
#pragma unroll 16
    for (int t = 0; t < LROWS; ++t) {
        float4 v = xp[(size_t)t * (C_DIM / 4)];
        run.x = fmaf(run.x, beta, v.x);
        run.y = fmaf(run.y, beta, v.y);
        run.z = fmaf(run.z, beta, v.z);
        run.w = fmaf(run.w, beta, v.w);
        op[(size_t)t * (C_DIM / 4)] = run;
    }
}

extern "C" void kernel_launch(void* const* d_in, const int* in_sizes, int n_in,
                              void* d_out, int out_size, void* d_ws, size_t ws_size,
                              hipStream_t stream) {
    const float* x      = (const float*)d_in[0];   // [T, B, D] fp32
    const float* beta_p = (const float*)d_in[1];   // scalar fp32
    float* out          = (float*)d_out;
    float* carry        = (float*)d_ws;            // CHUNKS * C_DIM floats = 1 MiB

    dim3 grid(COLTILES * CHUNKS);                  // 256 blocks
    dim3 block(NTHREADS);
    hipLaunchKernelGGL(k1_carries, grid, block, 0, stream, x, beta_p, carry);
    hipLaunchKernelGGL(k2_apply,   grid, block, 0, stream, x, beta_p, carry, out);
}

// Round 3
// 116.277 us; speedup vs baseline: 1.0780x; 1.0780x over previous
//
#include <hip/hip_runtime.h>
#include <math.h>

// (T, B, D) = (1024, 16, 1024); C = B*D = 16384 independent column scans
// y[t] = beta * y[t-1] + x[t],  beta = sigmoid(beta_param)
// Single-pass blocked scan: block = 64 columns x full T; 16 waves each own a
// 64-row chunk held in registers. One global read + one global write per
// element (134 MB total = the traffic floor). Non-temporal loads/stores:
// x is read exactly once and y never re-read, so bypass L2/L3 allocation.
#define T_DIM 1024
#define C_DIM 16384
#define WAVES 16
#define BLOCK_T (WAVES * 64)     // 1024 threads
#define L_CHUNK (T_DIM / WAVES)  // 64 rows per wave

__global__ __launch_bounds__(BLOCK_T, 4)
void pli_scan_kernel(const float* __restrict__ x,
                     const float* __restrict__ beta_p,
                     float* __restrict__ out) {
    const int lane = threadIdx.x & 63;
    const int w    = threadIdx.x >> 6;           // wave id = T-chunk id
    const int col  = (blockIdx.x << 6) + lane;   // this lane's column

    const float beta = 1.0f / (1.0f + expf(-beta_p[0]));

    const size_t base = (size_t)(w * L_CHUNK) * C_DIM + col;
    const float* xp = x + base;

    // Stage the chunk in registers: 64 coalesced non-temporal loads
    float v[L_CHUNK];
#pragma unroll
    for (int t = 0; t < L_CHUNK; ++t) {
        v[t] = __builtin_nontemporal_load(xp + (size_t)t * C_DIM);
    }

    // Local (zero-initialized) scan in place
    float run = 0.0f;
#pragma unroll
    for (int t = 0; t < L_CHUNK; ++t) {
        run = fmaf(run, beta, v[t]);
        v[t] = run;
    }

    // Exchange per-chunk carries through LDS
    __shared__ float carry[WAVES][64];
    carry[w][lane] = run;
    __syncthreads();

    // beta^64 via repeated squaring
    float bL = beta;
#pragma unroll
    for (int i = 0; i < 6; ++i) bL *= bL;

    // Prefix for this chunk: Y = full-scan value at row (w*L_CHUNK - 1)
    float Y = 0.0f;
    for (int u = 0; u < w; ++u) {                // wave-uniform trip count
        Y = fmaf(Y, bL, carry[u][lane]);
    }

    // y[s+t] = local[t] + beta^(t+1) * Y ; non-temporal stores
    float m = beta * Y;
    float* op = out + base;
#pragma unroll
    for (int t = 0; t < L_CHUNK; ++t) {
        __builtin_nontemporal_store(v[t] + m, op + (size_t)t * C_DIM);
        m *= beta;
    }
}

extern "C" void kernel_launch(void* const* d_in, const int* in_sizes, int n_in,
                              void* d_out, int out_size, void* d_ws, size_t ws_size,
                              hipStream_t stream) {
    const float* x      = (const float*)d_in[0];   // [T, B, D] fp32
    const float* beta_p = (const float*)d_in[1];   // scalar fp32
    float* out          = (float*)d_out;

    dim3 grid(C_DIM / 64);   // 256 blocks, one per CU
    dim3 block(BLOCK_T);     // 1024 threads = 16 waves
    hipLaunchKernelGGL(pli_scan_kernel, grid, block, 0, stream, x, beta_p, out);
}

// Round 4
// 115.080 us; speedup vs baseline: 1.0893x; 1.0104x over previous
//
#include <hip/hip_runtime.h>
#include <math.h>

// (T, B, D) = (1024, 16, 1024); C = B*D = 16384 independent column scans
// y[t] = beta * y[t-1] + x[t],  beta = sigmoid(beta_param)
// Single-pass blocked scan: block = 64 columns x full T; 16 waves each own a
// 64-row chunk held in registers. One global read + one global write per
// element (134 MB = traffic floor). Loads are non-temporal (x never reused;
// keep it out of L2/L3), stores are PLAIN (L2 write aggregation matters —
// nt stores measured -5us regression in R3).
#define T_DIM 1024
#define C_DIM 16384
#define WAVES 16
#define BLOCK_T (WAVES * 64)     // 1024 threads
#define L_CHUNK (T_DIM / WAVES)  // 64 rows per wave

__global__ __launch_bounds__(BLOCK_T, 4)
void pli_scan_kernel(const float* __restrict__ x,
                     const float* __restrict__ beta_p,
                     float* __restrict__ out) {
    const int lane = threadIdx.x & 63;
    const int w    = threadIdx.x >> 6;           // wave id = T-chunk id
    const int col  = (blockIdx.x << 6) + lane;   // this lane's column

    const float beta = 1.0f / (1.0f + expf(-beta_p[0]));

    const size_t base = (size_t)(w * L_CHUNK) * C_DIM + col;
    const float* xp = x + base;

    // Stage the chunk in registers: 64 coalesced non-temporal loads
    float v[L_CHUNK];
#pragma unroll
    for (int t = 0; t < L_CHUNK; ++t) {
        v[t] = __builtin_nontemporal_load(xp + (size_t)t * C_DIM);
    }

    // Local (zero-initialized) scan in place
    float run = 0.0f;
#pragma unroll
    for (int t = 0; t < L_CHUNK; ++t) {
        run = fmaf(run, beta, v[t]);
        v[t] = run;
    }

    // Exchange per-chunk carries through LDS
    __shared__ float carry[WAVES][64];
    carry[w][lane] = run;
    __syncthreads();

    // beta^64 via repeated squaring
    float bL = beta;
#pragma unroll
    for (int i = 0; i < 6; ++i) bL *= bL;

    // Prefix for this chunk: Y = full-scan value at row (w*L_CHUNK - 1)
    float Y = 0.0f;
    for (int u = 0; u < w; ++u) {                // wave-uniform trip count
        Y = fmaf(Y, bL, carry[u][lane]);
    }

    // y[s+t] = local[t] + beta^(t+1) * Y ; plain stores (keep L2 aggregation)
    float m = beta * Y;
    float* op = out + base;
#pragma unroll
    for (int t = 0; t < L_CHUNK; ++t) {
        op[(size_t)t * C_DIM] = v[t] + m;
        m *= beta;
    }
}

extern "C" void kernel_launch(void* const* d_in, const int* in_sizes, int n_in,
                              void* d_out, int out_size, void* d_ws, size_t ws_size,
                              hipStream_t stream) {
    const float* x      = (const float*)d_in[0];   // [T, B, D] fp32
    const float* beta_p = (const float*)d_in[1];   // scalar fp32
    float* out          = (float*)d_out;

    dim3 grid(C_DIM / 64);   // 256 blocks, one per CU
    dim3 block(BLOCK_T);     // 1024 threads = 16 waves
    hipLaunchKernelGGL(pli_scan_kernel, grid, block, 0, stream, x, beta_p, out);
}